// Round 2
// baseline (758.160 us; speedup 1.0000x reference)
//
#include <hip/hip_runtime.h>
#include <hip/hip_bf16.h>
#include <cstdint>

#define HFEAT 128
#define CIN   256

// ---------------- CSR build ----------------

__global__ void k_zero_i32(int* __restrict__ p, int n){
  int i = blockIdx.x*blockDim.x + threadIdx.x;
  if (i < n) p[i] = 0;
}

__global__ void k_count(const int* __restrict__ dst, int E, int* __restrict__ counts){
  int e = blockIdx.x*blockDim.x + threadIdx.x;
  if (e < E) atomicAdd(&counts[dst[e]], 1);
}

__global__ void k_dinv(const int* __restrict__ counts, int n, float* __restrict__ dinv){
  int i = blockIdx.x*blockDim.x + threadIdx.x;
  if (i < n) dinv[i] = rsqrtf((float)counts[i] + 1.0f);
}

__global__ void k_scan1(const int* __restrict__ counts, int n,
                        int* __restrict__ excl, int* __restrict__ bsum){
  __shared__ int sm[1024];
  int t = threadIdx.x;
  int i = blockIdx.x*1024 + t;
  int v = (i < n) ? counts[i] : 0;
  sm[t] = v;
  __syncthreads();
  for (int off = 1; off < 1024; off <<= 1){
    int add = (t >= off) ? sm[t-off] : 0;
    __syncthreads();
    sm[t] += add;
    __syncthreads();
  }
  if (i < n) excl[i] = sm[t] - v;
  if (t == 1023) bsum[blockIdx.x] = sm[t];
}

__global__ void k_scan2(int* __restrict__ bsum, int nb){
  if (threadIdx.x == 0 && blockIdx.x == 0){
    int run = 0;
    for (int b = 0; b < nb; b++){ int v = bsum[b]; bsum[b] = run; run += v; }
  }
}

__global__ void k_scan3(const int* __restrict__ bsum, int n, int E,
                        int* __restrict__ rowoff, int* __restrict__ cursor){
  int i = blockIdx.x*blockDim.x + threadIdx.x;   // blockDim == 1024
  if (i < n){
    int v = rowoff[i] + bsum[blockIdx.x];
    rowoff[i] = v;
    cursor[i] = v;
  }
  if (i == 0) rowoff[n] = E;
}

__global__ void k_fill(const int* __restrict__ src, const int* __restrict__ dst, int E,
                       const float* __restrict__ dinv, int* __restrict__ cursor,
                       int2* __restrict__ csr){
  int e = blockIdx.x*blockDim.x + threadIdx.x;
  if (e < E){
    int s = src[e], d = dst[e];
    int pos = atomicAdd(&cursor[d], 1);
    csr[pos] = make_int2(s, __float_as_int(dinv[s]*dinv[d]));
  }
}

// ---------------- GEMMs (fp32 vector ALU) ----------------

// out[N,128] = x[N,256] @ W[256,128]; 16 rows/block, 16 col-threads x 8 cols
__global__ void __launch_bounds__(256) k_gemm1(const float* __restrict__ x,
                                               const float* __restrict__ W,
                                               float* __restrict__ out, int n){
  int t = threadIdx.x;
  int c0 = (t & 15) * 8;
  int row = blockIdx.x * 16 + (t >> 4);
  if (row >= n) return;
  const float* xr = x + (size_t)row * CIN;
  float acc[8] = {0,0,0,0,0,0,0,0};
  #pragma unroll 4
  for (int k = 0; k < CIN; k += 4){
    float4 xv = *(const float4*)(xr + k);
    const float* wp = W + (size_t)k * HFEAT + c0;
    #pragma unroll
    for (int kk = 0; kk < 4; kk++){
      float xs = (kk==0) ? xv.x : (kk==1) ? xv.y : (kk==2) ? xv.z : xv.w;
      float4 w0 = *(const float4*)(wp + kk*HFEAT);
      float4 w1 = *(const float4*)(wp + kk*HFEAT + 4);
      acc[0] = fmaf(xs, w0.x, acc[0]);
      acc[1] = fmaf(xs, w0.y, acc[1]);
      acc[2] = fmaf(xs, w0.z, acc[2]);
      acc[3] = fmaf(xs, w0.w, acc[3]);
      acc[4] = fmaf(xs, w1.x, acc[4]);
      acc[5] = fmaf(xs, w1.y, acc[5]);
      acc[6] = fmaf(xs, w1.z, acc[6]);
      acc[7] = fmaf(xs, w1.w, acc[7]);
    }
  }
  float* op = out + (size_t)row * HFEAT + c0;
  *(float4*)op     = make_float4(acc[0],acc[1],acc[2],acc[3]);
  *(float4*)(op+4) = make_float4(acc[4],acc[5],acc[6],acc[7]);
}

// out(mu)=g@Wmu+bmu, out(ls)=g@Wls+bls; 8 rows/block, 32 col-threads x 8 cols (256 cols)
__global__ void __launch_bounds__(256) k_gemm2(const float* __restrict__ g,
                                               const float* __restrict__ Wmu,
                                               const float* __restrict__ Wls,
                                               const float* __restrict__ bmu,
                                               const float* __restrict__ bls,
                                               float* __restrict__ out, int n){
  int t = threadIdx.x;
  int c = (t & 31) * 8;
  int row = blockIdx.x * 8 + (t >> 5);
  if (row >= n) return;
  bool is_mu = (c < 128);
  const float* W = is_mu ? Wmu : Wls;
  const float* b = is_mu ? bmu : bls;
  float* o = is_mu ? out : out + (size_t)n * HFEAT;
  int cc = c & 127;
  const float* gr = g + (size_t)row * HFEAT;
  float acc[8] = {0,0,0,0,0,0,0,0};
  #pragma unroll 4
  for (int k = 0; k < HFEAT; k += 4){
    float4 xv = *(const float4*)(gr + k);
    const float* wp = W + (size_t)k * 128 + cc;
    #pragma unroll
    for (int kk = 0; kk < 4; kk++){
      float xs = (kk==0) ? xv.x : (kk==1) ? xv.y : (kk==2) ? xv.z : xv.w;
      float4 w0 = *(const float4*)(wp + kk*128);
      float4 w1 = *(const float4*)(wp + kk*128 + 4);
      acc[0] = fmaf(xs, w0.x, acc[0]);
      acc[1] = fmaf(xs, w0.y, acc[1]);
      acc[2] = fmaf(xs, w0.z, acc[2]);
      acc[3] = fmaf(xs, w0.w, acc[3]);
      acc[4] = fmaf(xs, w1.x, acc[4]);
      acc[5] = fmaf(xs, w1.y, acc[5]);
      acc[6] = fmaf(xs, w1.z, acc[6]);
      acc[7] = fmaf(xs, w1.w, acc[7]);
    }
  }
  float* op = o + (size_t)row * HFEAT + cc;
  *(float4*)op     = make_float4(acc[0]+b[cc],   acc[1]+b[cc+1], acc[2]+b[cc+2], acc[3]+b[cc+3]);
  *(float4*)(op+4) = make_float4(acc[4]+b[cc+4], acc[5]+b[cc+5], acc[6]+b[cc+6], acc[7]+b[cc+7]);
}

// ---------------- Aggregation: out = A_norm @ in (one wave per node) ----------------

template<int RELU>
__global__ void __launch_bounds__(256) k_agg(const float* __restrict__ in,
                                             const float* __restrict__ bias,
                                             const int* __restrict__ rowoff,
                                             const int2* __restrict__ csr,
                                             const float* __restrict__ dinv,
                                             float* __restrict__ out, int n){
  int gid = blockIdx.x*blockDim.x + threadIdx.x;
  int node = gid >> 6;
  int lane = gid & 63;
  if (node >= n) return;
  float di = dinv[node];
  float sw = di * di;
  int f0 = lane * 2;
  float2 sv = *(const float2*)(in + (size_t)node * HFEAT + f0);
  float ax = sv.x * sw, ay = sv.y * sw;
  int e = rowoff[node], e1 = rowoff[node+1];
  for (; e + 2 <= e1; e += 2){
    int2 c0 = csr[e], c1 = csr[e+1];
    float w0 = __int_as_float(c0.y), w1 = __int_as_float(c1.y);
    float2 v0 = *(const float2*)(in + (size_t)c0.x * HFEAT + f0);
    float2 v1 = *(const float2*)(in + (size_t)c1.x * HFEAT + f0);
    ax = fmaf(v0.x, w0, ax); ay = fmaf(v0.y, w0, ay);
    ax = fmaf(v1.x, w1, ax); ay = fmaf(v1.y, w1, ay);
  }
  if (e < e1){
    int2 c0 = csr[e];
    float w0 = __int_as_float(c0.y);
    float2 v0 = *(const float2*)(in + (size_t)c0.x * HFEAT + f0);
    ax = fmaf(v0.x, w0, ax); ay = fmaf(v0.y, w0, ay);
  }
  if (RELU){
    ax = fmaxf(ax + bias[f0],   0.f);
    ay = fmaxf(ay + bias[f0+1], 0.f);
  }
  *(float2*)(out + (size_t)node * HFEAT + f0) = make_float2(ax, ay);
}

// ---------------- launch ----------------

extern "C" void kernel_launch(void* const* d_in, const int* in_sizes, int n_in,
                              void* d_out, int out_size, void* d_ws, size_t ws_size,
                              hipStream_t stream){
  const float* x   = (const float*)d_in[0];
  const int*   ei  = (const int*)  d_in[1];
  const float* W1  = (const float*)d_in[2];
  const float* b1  = (const float*)d_in[3];
  const float* Wmu = (const float*)d_in[4];
  const float* bmu = (const float*)d_in[5];
  const float* Wls = (const float*)d_in[6];
  const float* bls = (const float*)d_in[7];
  int N = in_sizes[0] / CIN;
  int E = in_sizes[1] / 2;
  const int* src = ei;
  const int* dst = ei + E;
  float* out = (float*)d_out;

  char* w = (char*)d_ws;
  auto alloc = [&](size_t bytes)->char*{
    char* p = w; w += (bytes + 255) & ~(size_t)255; return p;
  };
  float* hW1   = (float*)alloc((size_t)N*HFEAT*4);   // later reused as g
  float* h     = (float*)alloc((size_t)N*HFEAT*4);
  int*   counts= (int*)  alloc((size_t)N*4);
  float* dinv  = (float*)alloc((size_t)N*4);
  int*   rowoff= (int*)  alloc(((size_t)N+1)*4);
  int*   cursor= (int*)  alloc((size_t)N*4);
  int*   bsum  = (int*)  alloc(256*4);
  int2*  csr   = (int2*) alloc((size_t)E*8);

  int nbN  = (N + 255) / 256;
  int nbE  = (E + 255) / 256;
  int nbS  = (N + 1023) / 1024;

  k_zero_i32<<<nbN, 256, 0, stream>>>(counts, N);
  k_count   <<<nbE, 256, 0, stream>>>(dst, E, counts);
  k_dinv    <<<nbN, 256, 0, stream>>>(counts, N, dinv);
  k_scan1   <<<nbS, 1024, 0, stream>>>(counts, N, rowoff, bsum);
  k_scan2   <<<1, 64, 0, stream>>>(bsum, nbS);
  k_scan3   <<<nbS, 1024, 0, stream>>>(bsum, N, E, rowoff, cursor);
  k_fill    <<<nbE, 256, 0, stream>>>(src, dst, E, dinv, cursor, csr);

  k_gemm1<<<(N + 15)/16, 256, 0, stream>>>(x, W1, hW1, N);
  int aggBlocks = (int)(((size_t)N*64 + 255) / 256);
  k_agg<1><<<aggBlocks, 256, 0, stream>>>(hW1, b1, rowoff, csr, dinv, h, N);
  float* g = hW1;  // hW1 dead after agg1
  k_agg<0><<<aggBlocks, 256, 0, stream>>>(h, nullptr, rowoff, csr, dinv, g, N);
  k_gemm2<<<(N + 7)/8, 256, 0, stream>>>(g, Wmu, Wls, bmu, bls, out, N);
}